// Round 11
// baseline (401.080 us; speedup 1.0000x reference)
//
#include <hip/hip_runtime.h>

// RVQ: z [16,64,4096] f32, codebooks [8,1024,64] f32 -> zq + 8 losses + 8 perplexities
#define S      8
#define K      1024
#define D      64
#define NVEC   65536
#define NBLK   2048      // 2-wave blocks, 32 vectors each (dual row-set, LDS-shared)
#define NWL    4096      // loss partials (one per wave)
#define NELEM  4194304.0f
#define EPSQ   1e-10f
#define DELTA  0.005f    // exact-rescan margin >> split-bf16 score error (~2e-3 worst)

typedef __attribute__((ext_vector_type(8))) short  short8;   // 8 bf16
typedef __attribute__((ext_vector_type(4))) float  float4v;  // MFMA acc

static __device__ inline unsigned short f2bf(float f) {
    unsigned int u = __float_as_uint(f);
    u = (u + 0x7FFFu + ((u >> 16) & 1u)) >> 16;
    return (unsigned short)u;
}
static __device__ inline float bf2f(unsigned short h) {
    return __uint_as_float(((unsigned int)h) << 16);
}

// ---------------------------------------------------------------------------
// Prep: (a) c2 + zero cnt; (b) interleave codebook into B-fragment streaming
// records, PRE-SCALED BY -2 so the MFMA accumulates -2*dot directly and the
// accumulator is seeded with c2 (score = acc, no per-score fmaf).
// Record = 4KB per (stage, 16-cw tile): segments at byte 0/1024/2048/3072
// ([h0h][h1h][h0l][h1l]), each segment 64 lanes x 16B.
// ---------------------------------------------------------------------------
__global__ void rvq_prep(const float* __restrict__ cb,
                         unsigned short* __restrict__ cbi,
                         float* __restrict__ c2, unsigned* __restrict__ cnt) {
    int i = blockIdx.x * blockDim.x + threadIdx.x;   // 0..32767
    if (i < S * K) {   // c2 + cnt zero
        const float* row = cb + (size_t)i * D;
        float a0 = 0.f, a1 = 0.f, a2 = 0.f, a3 = 0.f;
#pragma unroll
        for (int d = 0; d < D; d += 4) {
            a0 = fmaf(row[d+0], row[d+0], a0);
            a1 = fmaf(row[d+1], row[d+1], a1);
            a2 = fmaf(row[d+2], row[d+2], a2);
            a3 = fmaf(row[d+3], row[d+3], a3);
        }
        c2[i] = (a0 + a1) + (a2 + a3);
        cnt[i] = 0u;
    }
    // interleave: i = s*4096 + tau*64 + l
    int s  = i >> 12;
    int tau = (i >> 6) & 63;
    int l  = i & 63;
    int m  = l & 15, qq = l >> 4;
    const float* row = cb + (size_t)(s * K + tau * 16 + m) * D;
    short8 h0h, h0l, h1h, h1l;
#pragma unroll
    for (int e = 0; e < 8; ++e) {
        float x = -2.0f * row[qq * 8 + e];
        unsigned short h = f2bf(x);
        h0h[e] = (short)h; h0l[e] = (short)f2bf(x - bf2f(h));
        float y = -2.0f * row[32 + qq * 8 + e];
        unsigned short g = f2bf(y);
        h1h[e] = (short)g; h1l[e] = (short)f2bf(y - bf2f(g));
    }
    unsigned short* rec = cbi + (size_t)(s * 64 + tau) * 2048 + l * 8;
    *(short8*)(rec +    0) = h0h;
    *(short8*)(rec +  512) = h1h;
    *(short8*)(rec + 1024) = h0l;
    *(short8*)(rec + 1536) = h1l;
}

// ---------------------------------------------------------------------------
// Main (R11): R10 core + codebook-split 2-wave blocks (R2 idea, now viable).
// R10 post-mortem: 4-chain ILP + diet worked (420->330us, MfmaUtil 28) but
// the config is GRID-LIMITED: 2048 waves = 2/SIMD, occupancy 17%. R2's
// codebook split failed from duplicated tail + duplicated residual state;
// both are fixed by R10's LDS-resident residuals:
//  - both waves share rsp[] (no duplicated residual regs),
//  - wave w scans tiles [w*32, w*32+32) (scan work halves per wave),
//  - top-2 merged via tiny LDS exchange (tie -> lower k, converges to w0),
//  - tail SPLIT: wave 0 owns set-a rescue/update/loss/hist, wave 1 set-b;
//    only the cheap frag rebuild (~200 VALU) is duplicated.
// -> 4096 waves = 4/SIMD with R10's per-tile ILP intact, 3 barriers/stage.
//
// launch_bounds EMPIRICAL RULE: VGPR cap = 256/arg2 on this toolchain.
// arg2 MUST stay 2 (cap 128; (128,2) measured 124 OK in R2). (x,4) -> 64
// cap -> catastrophic spill, observed twice.
// ---------------------------------------------------------------------------
__global__ __launch_bounds__(128, 2)
void rvq_main(const float* __restrict__ z, const float* __restrict__ cbf,
              const unsigned short* __restrict__ cbi,
              const float* __restrict__ c2, float* __restrict__ zq,
              float* __restrict__ lossp, unsigned* __restrict__ cnt) {
    const int tid  = threadIdx.x;
    const int lane = tid & 63;
    const int w    = tid >> 6;              // wave 0/1
    const int m    = lane & 15;
    const int q    = lane >> 4;
    const int bid  = blockIdx.x;
    const int vbase = bid * 32;
    const int b    = vbase >> 12;
    const int ta   = (vbase & 4095) + m;    // set-a t (rows 0..15)
    const int tb   = ta + 16;               // set-b t (rows 16..31)
    const size_t zrow = ((size_t)(b * 64)) << 12;
    const int lo16 = lane * 16;     // per-lane byte offset into a segment
    const int lom  = m * 4;         // per-lane byte offset into c2 tile
    const int tbase = w * 32;       // this wave's tile range

    __shared__ float rsp[32][65];           // residual spill, +1 pad (8.3 KB)
    __shared__ float lb1[2][2][16];         // [wave][set][row] merge exchange
    __shared__ float lb2[2][2][16];
    __shared__ int   lk1[2][2][16];

    // ---- init: residuals <- z (wave 0: set a rows, wave 1: set b rows) ----
#pragma unroll
    for (int i = 0; i < 8; ++i) {
        if (w == 0) {
            rsp[m][q*8+i]       = z[zrow + ((size_t)(q*8+i)    << 12) + ta];
            rsp[m][32+q*8+i]    = z[zrow + ((size_t)(32+q*8+i) << 12) + ta];
        } else {
            rsp[16+m][q*8+i]    = z[zrow + ((size_t)(q*8+i)    << 12) + tb];
            rsp[16+m][32+q*8+i] = z[zrow + ((size_t)(32+q*8+i) << 12) + tb];
        }
    }
    __syncthreads();

// load one 4KB tile record + its c2 scalar; advance uniform bases (SALU)
#define LOADB(i) {                                                           \
        B##i##0 = *(const short8*)(tp + lo16);                               \
        B##i##1 = *(const short8*)(tp + lo16 + 1024);                        \
        B##i##2 = *(const short8*)(tp + lo16 + 2048);                        \
        B##i##3 = *(const short8*)(tp + lo16 + 3072);                        \
        cc##i   = *(const float*)(cp + lom);                                 \
        tp += 4096; cp += 64;                                                \
    }

#define MF(A,B,C) __builtin_amdgcn_mfma_f32_16x16x32_bf16(A,B,C,0,0,0)

// 12 MFMA as 4 independent 3-chains (2 per row-set: dims 0-31 / 32-63)
#define COMPUTE(i, tt) {                                                     \
        float4v p0 = {cc##i, cc##i, cc##i, cc##i};                           \
        float4v p1 = {0.f, 0.f, 0.f, 0.f};                                   \
        float4v r0 = {cc##i, cc##i, cc##i, cc##i};                           \
        float4v r1 = {0.f, 0.f, 0.f, 0.f};                                   \
        __builtin_amdgcn_s_setprio(1);                                       \
        p0 = MF(xa0h, B##i##0, p0); r0 = MF(xb0h, B##i##0, r0);              \
        p1 = MF(xa1h, B##i##1, p1); r1 = MF(xb1h, B##i##1, r1);              \
        p0 = MF(xa0l, B##i##0, p0); r0 = MF(xb0l, B##i##0, r0);              \
        p1 = MF(xa1l, B##i##1, p1); r1 = MF(xb1l, B##i##1, r1);              \
        p0 = MF(xa0h, B##i##2, p0); r0 = MF(xb0h, B##i##2, r0);              \
        p1 = MF(xa1h, B##i##3, p1); r1 = MF(xb1h, B##i##3, r1);              \
        __builtin_amdgcn_s_setprio(0);                                       \
        const int ncol = (tbase + (tt)) * 16 + m;                            \
        _Pragma("unroll")                                                    \
        for (int j = 0; j < 4; ++j) {                                        \
            float sa = p0[j] + p1[j];                                        \
            b2a[j] = __builtin_amdgcn_fmed3f(sa, b1a[j], b2a[j]);            \
            k1a[j] = (sa < b1a[j]) ? ncol : k1a[j];                          \
            b1a[j] = fminf(sa, b1a[j]);                                      \
            float sb = r0[j] + r1[j];                                        \
            b2b[j] = __builtin_amdgcn_fmed3f(sb, b1b[j], b2b[j]);            \
            k1b[j] = (sb < b1b[j]) ? ncol : k1b[j];                          \
            b1b[j] = fminf(sb, b1b[j]);                                      \
        }                                                                    \
    }

#pragma unroll 1
    for (int s = 0; s < S; ++s) {
        // ---- rebuild bf16 hi/lo A-fragments from LDS residuals (both waves)
        short8 xa0h, xa0l, xa1h, xa1l, xb0h, xb0l, xb1h, xb1l;
#pragma unroll
        for (int i = 0; i < 8; ++i) {
            unsigned short h; float v;
            v = rsp[m][q*8+i];        h = f2bf(v); xa0h[i] = (short)h; xa0l[i] = (short)f2bf(v - bf2f(h));
            v = rsp[m][32+q*8+i];     h = f2bf(v); xa1h[i] = (short)h; xa1l[i] = (short)f2bf(v - bf2f(h));
            v = rsp[16+m][q*8+i];     h = f2bf(v); xb0h[i] = (short)h; xb0l[i] = (short)f2bf(v - bf2f(h));
            v = rsp[16+m][32+q*8+i];  h = f2bf(v); xb1h[i] = (short)h; xb1l[i] = (short)f2bf(v - bf2f(h));
        }

        float b1a[4], b2a[4], b1b[4], b2b[4];
        int   k1a[4], k1b[4];
#pragma unroll
        for (int j = 0; j < 4; ++j) {
            b1a[j] = 3.4e38f; b2a[j] = 3.4e38f; k1a[j] = 0;
            b1b[j] = 3.4e38f; b2b[j] = 3.4e38f; k1b[j] = 0;
        }

        const float* c2s = c2 + s * K;
        const char*  tp  = (const char*)(cbi + (size_t)s * 131072) + tbase * 4096;
        const char*  cp  = (const char*)c2s + tbase * 64;

        short8 B00, B01, B02, B03, B10, B11, B12, B13;  // two banks
        float  cc0, cc1;

        LOADB(0) LOADB(1)

#pragma unroll 1
        for (int it = 0; it < 15; ++it) {
            const int tau = it * 2;
            COMPUTE(0, tau + 0) LOADB(0)     // reload tile tau+2
            COMPUTE(1, tau + 1) LOADB(1)     // reload tile tau+3
        }
        COMPUTE(0, 30) COMPUTE(1, 31)

        // ---- reduce across the 16 col-lanes (k-tie: lowest k) ----
#pragma unroll
        for (int off = 1; off < 16; off <<= 1) {
#pragma unroll
            for (int j = 0; j < 4; ++j) {
                float o1 = __shfl_xor(b1a[j], off); int ok = __shfl_xor(k1a[j], off);
                float o2 = __shfl_xor(b2a[j], off);
                float n2 = fminf(fminf(b2a[j], o2), fmaxf(b1a[j], o1));
                bool tk = (o1 < b1a[j]) || (o1 == b1a[j] && ok < k1a[j]);
                k1a[j] = tk ? ok : k1a[j]; b1a[j] = fminf(b1a[j], o1); b2a[j] = n2;
                o1 = __shfl_xor(b1b[j], off); ok = __shfl_xor(k1b[j], off);
                o2 = __shfl_xor(b2b[j], off);
                n2 = fminf(fminf(b2b[j], o2), fmaxf(b1b[j], o1));
                tk = (o1 < b1b[j]) || (o1 == b1b[j] && ok < k1b[j]);
                k1b[j] = tk ? ok : k1b[j]; b1b[j] = fminf(b1b[j], o1); b2b[j] = n2;
            }
        }

        // ---- cross-wave merge via LDS (tie -> lower k; converges to w0) --
        if (m == 0) {
#pragma unroll
            for (int j = 0; j < 4; ++j) {
                lb1[w][0][q*4+j] = b1a[j]; lb2[w][0][q*4+j] = b2a[j];
                lk1[w][0][q*4+j] = k1a[j];
                lb1[w][1][q*4+j] = b1b[j]; lb2[w][1][q*4+j] = b2b[j];
                lk1[w][1][q*4+j] = k1b[j];
            }
        }
        __syncthreads();
        {
            int ow = w ^ 1;
#pragma unroll
            for (int j = 0; j < 4; ++j) {
                float o1 = lb1[ow][0][q*4+j], o2 = lb2[ow][0][q*4+j];
                int   ok = lk1[ow][0][q*4+j];
                float n2 = fminf(fminf(b2a[j], o2), fmaxf(b1a[j], o1));
                bool tk = (o1 < b1a[j]) || (o1 == b1a[j] && ok < k1a[j]);
                k1a[j] = tk ? ok : k1a[j]; b1a[j] = fminf(b1a[j], o1); b2a[j] = n2;
                o1 = lb1[ow][1][q*4+j]; o2 = lb2[ow][1][q*4+j];
                ok = lk1[ow][1][q*4+j];
                n2 = fminf(fminf(b2b[j], o2), fmaxf(b1b[j], o1));
                tk = (o1 < b1b[j]) || (o1 == b1b[j] && ok < k1b[j]);
                k1b[j] = tk ? ok : k1b[j]; b1b[j] = fminf(b1b[j], o1); b2b[j] = n2;
            }
        }

        // ---- δ-rescue (SPLIT: wave 0 -> set a, wave 1 -> set b) ----
        const float* cr0 = cbf + (size_t)s * 65536;
#define RESCUE(b1X, b2X, k1X, ROW)                                            \
        for (int j = 0; j < 4; ++j) {                                         \
            unsigned long long mask = __ballot(b2X[j] - b1X[j] < DELTA);      \
            while (mask) {                                                    \
                int lq = (int)(__builtin_ctzll(mask)) >> 4;                   \
                mask &= ~(0xFFFFULL << (lq * 16));                            \
                int mrow = lq * 4 + j;                                        \
                float bd = 3.4e38f; int bk = 0;                               \
                for (int cc = 0; cc < 16; ++cc) {                             \
                    int n = cc * 64 + lane;                                   \
                    const float* crow = cr0 + (size_t)n * 64;                 \
                    float dot = 0.f;                                          \
                    for (int d = 0; d < 64; ++d)                              \
                        dot = fmaf(rsp[(ROW) + mrow][d], crow[d], dot);       \
                    float sc = c2s[n] - 2.f * dot;                            \
                    if (sc < bd) { bd = sc; bk = n; }                         \
                }                                                             \
                for (int off = 1; off < 64; off <<= 1) {                      \
                    float ob = __shfl_xor(bd, off); int ok = __shfl_xor(bk, off); \
                    bool tk = (ob < bd) || (ob == bd && ok < bk);             \
                    bk = tk ? ok : bk; bd = fminf(bd, ob);                    \
                }                                                             \
                if (q == lq) k1X[j] = bk;                                     \
            }                                                                 \
        }
        if (w == 0) { RESCUE(b1a, b2a, k1a, 0) }
        else        { RESCUE(b1b, b2b, k1b, 16) }
#undef RESCUE

        // ---- transpose winners (own set only), update rsp + loss + hist ---
        int mm = m & 3, src = (m >> 2) * 16;
        float ls = 0.f;
        if (w == 0) {
            int wa0 = __shfl(k1a[0], src), wa1 = __shfl(k1a[1], src);
            int wa2 = __shfl(k1a[2], src), wa3 = __shfl(k1a[3], src);
            int bka = (mm == 0) ? wa0 : (mm == 1) ? wa1 : (mm == 2) ? wa2 : wa3;
            const float* qa = cbf + (size_t)s * 65536 + (size_t)bka * 64;
#pragma unroll
            for (int i = 0; i < 8; ++i) {
                float na = rsp[m][q*8+i]    - qa[q*8+i];
                float nb = rsp[m][32+q*8+i] - qa[32+q*8+i];
                rsp[m][q*8+i] = na;  rsp[m][32+q*8+i] = nb;
                ls = fmaf(na, na, ls); ls = fmaf(nb, nb, ls);
            }
            if (q == 0) atomicAdd(&cnt[s * K + bka], 1u);
        } else {
            int wb0 = __shfl(k1b[0], src), wb1 = __shfl(k1b[1], src);
            int wb2 = __shfl(k1b[2], src), wb3 = __shfl(k1b[3], src);
            int bkb = (mm == 0) ? wb0 : (mm == 1) ? wb1 : (mm == 2) ? wb2 : wb3;
            const float* qb = cbf + (size_t)s * 65536 + (size_t)bkb * 64;
#pragma unroll
            for (int i = 0; i < 8; ++i) {
                float nc = rsp[16+m][q*8+i]    - qb[q*8+i];
                float nd = rsp[16+m][32+q*8+i] - qb[32+q*8+i];
                rsp[16+m][q*8+i] = nc;  rsp[16+m][32+q*8+i] = nd;
                ls = fmaf(nc, nc, ls); ls = fmaf(nd, nd, ls);
            }
            if (q == 0) atomicAdd(&cnt[s * K + bkb], 1u);
        }
#pragma unroll
        for (int off = 1; off < 64; off <<= 1) ls += __shfl_xor(ls, off);
        if (lane == 0) lossp[s * NWL + bid * 2 + w] = ls;

        __syncthreads();   // rsp fully updated before next stage's rebuild
    }
#undef LOADB
#undef COMPUTE
#undef MF

    // ---- epilogue: zq = z - r_final (each wave stores its own set) ----
#pragma unroll
    for (int i = 0; i < 8; ++i) {
        if (w == 0) {
            size_t a0 = zrow + ((size_t)(q*8+i)    << 12) + ta;
            size_t a1 = zrow + ((size_t)(32+q*8+i) << 12) + ta;
            zq[a0] = z[a0] - rsp[m][q*8+i];
            zq[a1] = z[a1] - rsp[m][32+q*8+i];
        } else {
            size_t a2 = zrow + ((size_t)(q*8+i)    << 12) + tb;
            size_t a3 = zrow + ((size_t)(32+q*8+i) << 12) + tb;
            zq[a2] = z[a2] - rsp[16+m][q*8+i];
            zq[a3] = z[a3] - rsp[16+m][32+q*8+i];
        }
    }
}

// ---------------------------------------------------------------------------
// Finalize: losses (mean of summed wave partials) + perplexities
// ---------------------------------------------------------------------------
__global__ void rvq_finalize(const float* __restrict__ lossp,
                             const unsigned* __restrict__ cnt,
                             float* __restrict__ out_loss,
                             float* __restrict__ out_perp) {
    const int s   = blockIdx.x;
    const int tid = threadIdx.x;
    float ent = 0.f, lsum = 0.f;
    for (int i = tid; i < K; i += 256) {
        float p = (float)cnt[s * K + i] * (1.0f / 65536.0f);
        ent += p * logf(p + EPSQ);
    }
    for (int i = tid; i < NWL; i += 256) lsum += lossp[s * NWL + i];
    __shared__ float redE[4], redL[4];
#pragma unroll
    for (int off = 32; off > 0; off >>= 1) {
        ent  += __shfl_down(ent, off);
        lsum += __shfl_down(lsum, off);
    }
    if ((tid & 63) == 0) { redE[tid >> 6] = ent; redL[tid >> 6] = lsum; }
    __syncthreads();
    if (tid == 0) {
        float te = redE[0] + redE[1] + redE[2] + redE[3];
        float tl = redL[0] + redL[1] + redL[2] + redL[3];
        out_perp[s] = expf(-te);
        out_loss[s] = tl * (1.0f / NELEM);
    }
}

// ---------------------------------------------------------------------------
extern "C" void kernel_launch(void* const* d_in, const int* in_sizes, int n_in,
                              void* d_out, int out_size, void* d_ws, size_t ws_size,
                              hipStream_t stream) {
    const float* z  = (const float*)d_in[0];
    const float* cb = (const float*)d_in[1];

    float* zq       = (float*)d_out;
    float* out_loss = zq + 4194304;
    float* out_perp = out_loss + 8;

    // ws: cbi 2 MB | c2 32 KB | cnt 32 KB | lossp 128 KB
    char* ws = (char*)d_ws;
    unsigned short* cbi = (unsigned short*)(ws);
    float*    c2    = (float*)(ws + 2097152);
    unsigned* cnt   = (unsigned*)(ws + 2129920);
    float*    lossp = (float*)(ws + 2162688);

    hipLaunchKernelGGL(rvq_prep,     dim3(128),  dim3(256), 0, stream, cb, cbi, c2, cnt);
    hipLaunchKernelGGL(rvq_main,     dim3(NBLK), dim3(128), 0, stream, z, cb, cbi, c2, zq, lossp, cnt);
    hipLaunchKernelGGL(rvq_finalize, dim3(S),    dim3(256), 0, stream, lossp, cnt, out_loss, out_perp);
}